// Round 11
// baseline (1394.237 us; speedup 1.0000x reference)
//
#include <hip/hip_runtime.h>
#include <hip/hip_bf16.h>

typedef __bf16 bf16;
typedef __bf16 bf16x4 __attribute__((ext_vector_type(4)));
typedef __bf16 bf16x8 __attribute__((ext_vector_type(8)));
typedef float  f32x4  __attribute__((ext_vector_type(4)));

#define EDIM 1536
#define DDIM 128
#define CDIM 1664   // E + D
#define TM   32
#define NCHA 48     // phase A chunks of 32 k
#define NCHT 52     // + 4 phase B chunks

#define MFMA_B16(a, b, c) __builtin_amdgcn_mfma_f32_16x16x32_bf16((a), (b), (c), 0, 0, 0)

__device__ __forceinline__ float sigf(float x) { return 1.0f / (1.0f + __expf(-x)); }
__device__ __forceinline__ float tanhf_fast(float x) { return 2.0f / (1.0f + __expf(-2.0f * x)) - 1.0f; }

// f32 -> bf16 weight conversion into workspace
__global__ __launch_bounds__(256) void prep_convert(const float* __restrict__ w_ih,
                                                    const float* __restrict__ w_hh,
                                                    bf16* __restrict__ wib,
                                                    bf16* __restrict__ whb) {
  const int i = (blockIdx.x * 256 + threadIdx.x) * 4;
  const int TIH = 3 * DDIM * EDIM;
  const int THH = 3 * DDIM * DDIM;
  if (i < TIH) {
    const float4 v = *(const float4*)(w_ih + i);
    bf16x4 o = {(bf16)v.x, (bf16)v.y, (bf16)v.z, (bf16)v.w};
    *(bf16x4*)(wib + i) = o;
  } else if (i < TIH + THH) {
    const int j = i - TIH;
    const float4 v = *(const float4*)(w_hh + j);
    bf16x4 o = {(bf16)v.x, (bf16)v.y, (bf16)v.z, (bf16)v.w};
    *(bf16x4*)(whb + j) = o;
  }
}

// TM=32 rows, 256 thr = 4 waves; wave wn owns gate-cols [32*wn,+32).
// W reg-staged (R8-proven) into single 80B-padded sW (conflict-free reads),
// 2 barriers/chunk; A ping-pong register prefetch; ~39KB LDS -> 3 blocks/CU.
__global__ __launch_bounds__(256, 3) void gru_fused(
    const float* __restrict__ emb, const int* __restrict__ ids,
    const float* __restrict__ mem,
    const float* __restrict__ b_ih, const float* __restrict__ b_hh,
    const float* __restrict__ cls_w, const float* __restrict__ cls_b,
    const bf16* __restrict__ wib, const bf16* __restrict__ whb,
    float* __restrict__ logits, float* __restrict__ omem, int Nrows)
{
  __shared__ char  sW[30720];     // W chunk: 384 rows x 80B (64B data + 16B pad)
  __shared__ char  sU[8192];      // phase A: sA dbuf 2 x 2560B (32 rows x 80B)
                                  // phase B: sP 32 rows x 256B (R3 swizzle)
  __shared__ float sLp[32][2];
  __shared__ int   sIds[32];

  const int t    = threadIdx.x;
  const int lane = t & 63;
  const int wn   = t >> 6;        // wave = gate-col group 0..3
  const int l15  = lane & 15;
  const int lq   = lane >> 4;     // 0..3
  const int m0   = blockIdx.x * TM;

  if (t < 32) sIds[t] = (m0 + t < Nrows) ? ids[m0 + t] : 0;
  if (t < 64) sLp[t >> 1][t & 1] = cls_b[t & 1];

  // accumulators (r,z: b_ih+b_hh; n-gate split accN/accH) = 64 AGPR
  f32x4 accR[2][2], accZ[2][2], accN[2][2], accH[2][2];
#pragma unroll
  for (int sub = 0; sub < 2; ++sub) {
    const int nc = wn * 32 + sub * 16 + l15;
    const float br = b_ih[nc] + b_hh[nc];
    const float bz = b_ih[128 + nc] + b_hh[128 + nc];
    const float bn = b_ih[256 + nc];
    const float bh = b_hh[256 + nc];
#pragma unroll
    for (int mt = 0; mt < 2; ++mt) {
      accR[mt][sub] = (f32x4){br, br, br, br};
      accZ[mt][sub] = (f32x4){bz, bz, bz, bz};
      accN[mt][sub] = (f32x4){bn, bn, bn, bn};
      accH[mt][sub] = (f32x4){bh, bh, bh, bh};
    }
  }

  // A staging: thread t owns row arow = t>>3 (0..31), f32 quad aq = t&7
  const int  arow = t >> 3;
  const int  aq   = t & 7;
  const bool av   = (m0 + arow) < Nrows;
  const float* pA = emb + (size_t)(m0 + arow) * EDIM + aq * 4;
  const int  awofs = arow * 80 + aq * 8;     // 8B bf16x4 within 80B row
  const int  nb    = wn * 32 + l15;          // W read row base
  float lp0 = 0.f, lp1 = 0.f;

  uint4 wreg[6];
  const float4 fz = make_float4(0.f, 0.f, 0.f, 0.f);
  float4 aCur = fz, aNxt = fz;

  // W chunk load: 1536 segs / 256 thr = 6 each; 4 consecutive thr = 64B line
#define LOADW(CI) do {                                                         \
    const int ci_ = (CI);                                                      \
    const bf16* bse_; int lda_, k0_;                                           \
    if (ci_ < NCHA) { bse_ = wib; lda_ = EDIM; k0_ = ci_ * 32; }               \
    else            { bse_ = whb; lda_ = DDIM; k0_ = (ci_ - NCHA) * 32; }      \
    _Pragma("unroll")                                                          \
    for (int j_ = 0; j_ < 6; ++j_) {                                           \
      const int s_ = j_ * 256 + t;                                             \
      wreg[j_] = *(const uint4*)(bse_ + (size_t)(s_ >> 2) * lda_ + k0_ + (s_ & 3) * 8); \
    }                                                                          \
  } while (0)

#define STOREW() do {                                                          \
    _Pragma("unroll")                                                          \
    for (int j_ = 0; j_ < 6; ++j_) {                                           \
      const int s_ = j_ * 256 + t;                                             \
      *(uint4*)(sW + (s_ >> 2) * 80 + (s_ & 3) * 16) = wreg[j_];               \
    }                                                                          \
  } while (0)

#define STOREA(BUF, AR) do {                                                   \
    bf16x4 o_ = {(bf16)(AR).x, (bf16)(AR).y, (bf16)(AR).z, (bf16)(AR).w};      \
    *(bf16x4*)(sU + (BUF) * 2560 + awofs) = o_;                                \
  } while (0)

  // ---- prologue: W0 + A0 into LDS; issue W1, A1 ----
  LOADW(0);
  {
    float4 p = av ? *(const float4*)pA : fz;
    const float4 c0 = *(const float4*)(cls_w + aq * 4);
    const float4 c1 = *(const float4*)(cls_w + CDIM + aq * 4);
    lp0 += p.x * c0.x + p.y * c0.y + p.z * c0.z + p.w * c0.w;
    lp1 += p.x * c1.x + p.y * c1.y + p.z * c1.z + p.w * c1.w;
    STOREA(0, p);
  }
  STOREW();              // waits W0 loads, writes sW
  LOADW(1);              // in flight across body 0
  if (av) aCur = *(const float4*)(pA + 32);   // A slice 1
  __syncthreads();

  // ---- Phase A: 48 chunks, single-buffer sW, 2 barriers/chunk ----
  for (int C = 0; C < NCHA; ++C) {
    const int cur = C & 1, nxt = cur ^ 1;
    const bool pf = (C + 1) < NCHA;
    // issue next A load early (HBM latency hidden across this body)
    if (C + 2 < NCHA && av) aNxt = *(const float4*)(pA + (C + 2) * 32);
    // read all fragments for chunk C into regs (conflict-free, 80B pad)
    const bf16x8 af0 = *(bf16x8*)(sU + cur * 2560 + (l15) * 80 + lq * 16);
    const bf16x8 af1 = *(bf16x8*)(sU + cur * 2560 + (16 + l15) * 80 + lq * 16);
    const bf16x8 bR0 = *(bf16x8*)(sW + (nb      ) * 80 + lq * 16);
    const bf16x8 bR1 = *(bf16x8*)(sW + (nb +  16) * 80 + lq * 16);
    const bf16x8 bZ0 = *(bf16x8*)(sW + (nb + 128) * 80 + lq * 16);
    const bf16x8 bZ1 = *(bf16x8*)(sW + (nb + 144) * 80 + lq * 16);
    const bf16x8 bN0 = *(bf16x8*)(sW + (nb + 256) * 80 + lq * 16);
    const bf16x8 bN1 = *(bf16x8*)(sW + (nb + 272) * 80 + lq * 16);
    __syncthreads();                 // all reads of sW/sA done
    accR[0][0] = MFMA_B16(af0, bR0, accR[0][0]);
    accR[1][0] = MFMA_B16(af1, bR0, accR[1][0]);
    accR[0][1] = MFMA_B16(af0, bR1, accR[0][1]);
    accR[1][1] = MFMA_B16(af1, bR1, accR[1][1]);
    accZ[0][0] = MFMA_B16(af0, bZ0, accZ[0][0]);
    accZ[1][0] = MFMA_B16(af1, bZ0, accZ[1][0]);
    accZ[0][1] = MFMA_B16(af0, bZ1, accZ[0][1]);
    accZ[1][1] = MFMA_B16(af1, bZ1, accZ[1][1]);
    accN[0][0] = MFMA_B16(af0, bN0, accN[0][0]);
    accN[1][0] = MFMA_B16(af1, bN0, accN[1][0]);
    accN[0][1] = MFMA_B16(af0, bN1, accN[0][1]);
    accN[1][1] = MFMA_B16(af1, bN1, accN[1][1]);
    STOREW();                        // sW <- chunk C+1 (vmcnt wait overlaps MFMA)
    if (pf) {
      const int kc = (C + 1) * 32 + aq * 4;
      const float4 c0 = *(const float4*)(cls_w + kc);
      const float4 c1 = *(const float4*)(cls_w + CDIM + kc);
      lp0 += aCur.x * c0.x + aCur.y * c0.y + aCur.z * c0.z + aCur.w * c0.w;
      lp1 += aCur.x * c1.x + aCur.y * c1.y + aCur.z * c1.z + aCur.w * c1.w;
      STOREA(nxt, aCur);
      aCur = aNxt;
    }
    if (C + 2 < NCHT) LOADW(C + 2);  // issue next W chunk (L2)
    __syncthreads();                 // writes visible
  }

  // classifier emb-part: reduce over the 8 threads (aq) sharing row arow
  {
    lp0 += __shfl_xor(lp0, 1); lp0 += __shfl_xor(lp0, 2); lp0 += __shfl_xor(lp0, 4);
    lp1 += __shfl_xor(lp1, 1); lp1 += __shfl_xor(lp1, 2); lp1 += __shfl_xor(lp1, 4);
    if (aq == 0) {
      atomicAdd(&sLp[arow][0], lp0);
      atomicAdd(&sLp[arow][1], lp1);
    }
  }

  // ---- Phase B: gather prev -> sU (R3-proven swizzle), gh over K=128 ----
  // sW currently holds whb chunk 0 (stored in body 47); wreg holds chunk 1.
  {
    const int prow = t >> 5;            // 0..7
    const int pc   = t & 31;            // f32 quad: col = pc*4
#pragma unroll
    for (int p = 0; p < 4; ++p) {
      const int r = p * 8 + prow;
      const float4 v = *(const float4*)(mem + (size_t)sIds[r] * DDIM + pc * 4);
      bf16x4 o = {(bf16)v.x, (bf16)v.y, (bf16)v.z, (bf16)v.w};
      *(bf16x4*)(sU + r * 256 + ((pc << 3) ^ ((r & 7) << 4))) = o;
    }
  }
  __syncthreads();

#pragma unroll
  for (int ks = 0; ks < 4; ++ks) {
    bf16x8 af[2];
#pragma unroll
    for (int mt = 0; mt < 2; ++mt) {
      const int m = mt * 16 + l15;
      const int kb = (ks * 32 + lq * 8) << 1;
      af[mt] = *(bf16x8*)(sU + m * 256 + (kb ^ ((m & 7) << 4)));
    }
    const bf16x8 bR0 = *(bf16x8*)(sW + (nb      ) * 80 + lq * 16);
    const bf16x8 bR1 = *(bf16x8*)(sW + (nb +  16) * 80 + lq * 16);
    const bf16x8 bZ0 = *(bf16x8*)(sW + (nb + 128) * 80 + lq * 16);
    const bf16x8 bZ1 = *(bf16x8*)(sW + (nb + 144) * 80 + lq * 16);
    const bf16x8 bH0 = *(bf16x8*)(sW + (nb + 256) * 80 + lq * 16);
    const bf16x8 bH1 = *(bf16x8*)(sW + (nb + 272) * 80 + lq * 16);
    __syncthreads();                 // reads of sW chunk done
    accR[0][0] = MFMA_B16(af[0], bR0, accR[0][0]);
    accR[1][0] = MFMA_B16(af[1], bR0, accR[1][0]);
    accR[0][1] = MFMA_B16(af[0], bR1, accR[0][1]);
    accR[1][1] = MFMA_B16(af[1], bR1, accR[1][1]);
    accZ[0][0] = MFMA_B16(af[0], bZ0, accZ[0][0]);
    accZ[1][0] = MFMA_B16(af[1], bZ0, accZ[1][0]);
    accZ[0][1] = MFMA_B16(af[0], bZ1, accZ[0][1]);
    accZ[1][1] = MFMA_B16(af[1], bZ1, accZ[1][1]);
    accH[0][0] = MFMA_B16(af[0], bH0, accH[0][0]);
    accH[1][0] = MFMA_B16(af[1], bH0, accH[1][0]);
    accH[0][1] = MFMA_B16(af[0], bH1, accH[0][1]);
    accH[1][1] = MFMA_B16(af[1], bH1, accH[1][1]);
    if (ks < 3) {
      STOREW();                      // next whb chunk
      if (ks + 2 < 4) LOADW(NCHA + ks + 2);
    }
    __syncthreads();
  }

  // ---- Epilogue: gates, scatter new_mem, classifier mem-part ----
  float lpM[8][2];
#pragma unroll
  for (int i = 0; i < 8; ++i) { lpM[i][0] = 0.f; lpM[i][1] = 0.f; }

#pragma unroll
  for (int mt = 0; mt < 2; ++mt) {
#pragma unroll
    for (int sub = 0; sub < 2; ++sub) {
      const int d = wn * 32 + sub * 16 + l15;
      const float cw0 = cls_w[EDIM + d];
      const float cw1 = cls_w[CDIM + EDIM + d];
#pragma unroll
      for (int j = 0; j < 4; ++j) {
        const int m = mt * 16 + lq * 4 + j;
        const float r = sigf(accR[mt][sub][j]);
        const float z = sigf(accZ[mt][sub][j]);
        const float n = tanhf_fast(accN[mt][sub][j] + r * accH[mt][sub][j]);
        const float pv = mem[(size_t)sIds[m] * DDIM + d];
        const float nv = (1.0f - z) * n + z * pv;
        if (m0 + m < Nrows) omem[(size_t)sIds[m] * DDIM + d] = nv;
        lpM[mt * 4 + j][0] += nv * cw0;
        lpM[mt * 4 + j][1] += nv * cw1;
      }
    }
  }

#pragma unroll
  for (int i = 0; i < 8; ++i) {
#pragma unroll
    for (int c = 0; c < 2; ++c) {
      float v = lpM[i][c];
      v += __shfl_xor(v, 1); v += __shfl_xor(v, 2);
      v += __shfl_xor(v, 4); v += __shfl_xor(v, 8);
      if (l15 == 0) {
        const int m = (i >> 2) * 16 + lq * 4 + (i & 3);
        atomicAdd(&sLp[m][c], v);
      }
    }
  }
  __syncthreads();

  if (t < 64) {
    const int m = t >> 1, c = t & 1;
    if (m0 + m < Nrows) logits[(size_t)(m0 + m) * 2 + c] = sLp[m][c];
  }
#undef LOADW
#undef STOREW
#undef STOREA
}

extern "C" void kernel_launch(void* const* d_in, const int* in_sizes, int n_in,
                              void* d_out, int out_size, void* d_ws, size_t ws_size,
                              hipStream_t stream) {
  const float* emb   = (const float*)d_in[0];
  const int*   ids   = (const int*)d_in[1];
  const float* mem   = (const float*)d_in[2];
  const float* w_ih  = (const float*)d_in[3];
  const float* w_hh  = (const float*)d_in[4];
  const float* b_ih  = (const float*)d_in[5];
  const float* b_hh  = (const float*)d_in[6];
  const float* cls_w = (const float*)d_in[7];
  const float* cls_b = (const float*)d_in[8];

  const int N    = in_sizes[0] / EDIM;   // 100000
  const int MAXN = in_sizes[2] / DDIM;   // 250000

  float* logits = (float*)d_out;
  float* omem   = (float*)d_out + (size_t)N * 2;
  bf16*  wib    = (bf16*)d_ws;
  bf16*  whb    = wib + 3 * DDIM * EDIM;

  // 1) blanket copy memory -> out (scatter overwrites active rows)
  hipMemcpyAsync(omem, mem, (size_t)MAXN * DDIM * sizeof(float),
                 hipMemcpyDeviceToDevice, stream);
  // 2) weights to bf16
  const int prep_threads = (3 * DDIM * EDIM + 3 * DDIM * DDIM) / 4;
  prep_convert<<<(prep_threads + 255) / 256, 256, 0, stream>>>(w_ih, w_hh, wib, whb);
  // 3) fused GRU + classifier
  gru_fused<<<(N + TM - 1) / TM, 256, 0, stream>>>(emb, ids, mem, b_ih, b_hh,
                                                   cls_w, cls_b, wib, whb,
                                                   logits, omem, N);
}

// Round 12
// 441.932 us; speedup vs baseline: 3.1549x; 3.1549x over previous
//
#include <hip/hip_runtime.h>
#include <hip/hip_bf16.h>

typedef __bf16 bf16;
typedef __bf16 bf16x4 __attribute__((ext_vector_type(4)));
typedef __bf16 bf16x8 __attribute__((ext_vector_type(8)));
typedef float  f32x4  __attribute__((ext_vector_type(4)));

#define EDIM 1536
#define DDIM 128
#define CDIM 1664   // E + D
#define TM   64
#define NCH  48     // phase A chunks: 1536 / 32

#define MFMA_B16(a, b, c) __builtin_amdgcn_mfma_f32_16x16x32_bf16((a), (b), (c), 0, 0, 0)

__device__ __forceinline__ float sigf(float x) { return 1.0f / (1.0f + __expf(-x)); }
__device__ __forceinline__ float tanhf_fast(float x) { return 2.0f / (1.0f + __expf(-2.0f * x)) - 1.0f; }

__device__ __forceinline__ void glds16(const void* g, void* l) {
  __builtin_amdgcn_global_load_lds(
      (const __attribute__((address_space(1))) unsigned int*)g,
      (__attribute__((address_space(3))) unsigned int*)l, 16, 0, 0);
}

// R4-proven linear staging: slot s holds row s>>2, 16B k-seg s&3.
// Quarter-wave = 4 rows x 64B contiguous (coalesced). Zero registers held.
template <int LDA>
__device__ __forceinline__ void stageW(const bf16* __restrict__ w, int k0,
                                       char* dst, int wave, int lane) {
#pragma unroll
  for (int j = 0; j < 3; ++j) {
    const int segbase = j * 512 + wave * 64;     // wave-uniform
    const int s = segbase + lane;                // 0..1535
    const int n = s >> 2;                        // weight row 0..383
    const int q = s & 3;                         // 16B k-seg within chunk
    glds16(w + (size_t)n * LDA + k0 + q * 8, dst + (size_t)segbase * 16);
  }
}

// f32 -> bf16 weight conversion into workspace
__global__ __launch_bounds__(256) void prep_convert(const float* __restrict__ w_ih,
                                                    const float* __restrict__ w_hh,
                                                    bf16* __restrict__ wib,
                                                    bf16* __restrict__ whb) {
  const int i = (blockIdx.x * 256 + threadIdx.x) * 4;
  const int TIH = 3 * DDIM * EDIM;
  const int THH = 3 * DDIM * DDIM;
  if (i < TIH) {
    const float4 v = *(const float4*)(w_ih + i);
    bf16x4 o = {(bf16)v.x, (bf16)v.y, (bf16)v.z, (bf16)v.w};
    *(bf16x4*)(wib + i) = o;
  } else if (i < TIH + THH) {
    const int j = i - TIH;
    const float4 v = *(const float4*)(w_hh + j);
    bf16x4 o = {(bf16)v.x, (bf16)v.y, (bf16)v.z, (bf16)v.w};
    *(bf16x4*)(whb + j) = o;
  }
}

// R4 skeleton (TM=64, 512 thr, 8 waves, glds W dbuf, 1 barrier/chunk) plus
// distance-2 emb prefetch: slice C+2 issued at top of body C, consumed at
// bottom of body C+1. Only +8 VGPR over R4 (aCur/aNxt) -> no spill.
__global__ __launch_bounds__(512, 4) void gru_fused(
    const float* __restrict__ emb, const int* __restrict__ ids,
    const float* __restrict__ mem,
    const float* __restrict__ b_ih, const float* __restrict__ b_hh,
    const float* __restrict__ cls_w, const float* __restrict__ cls_b,
    const bf16* __restrict__ wib, const bf16* __restrict__ whb,
    float* __restrict__ logits, float* __restrict__ omem, int Nrows)
{
  __shared__ char  sW[2][24576];  // W chunk dbuf: 384 rows x 64B, linear (R4)
  __shared__ char  sA[2][5120];   // A slice dbuf: 64 rows x 80B
  __shared__ char  sP[16384];     // prev gathered: 64 rows x 256B (proven swizzle)
  __shared__ float sLp[64][2];
  __shared__ int   sIds[64];

  const int t    = threadIdx.x;
  const int lane = t & 63;
  const int wave = t >> 6;
  const int wm   = wave >> 2;     // 0..1
  const int wn   = wave & 3;      // 0..3
  const int l15  = lane & 15;
  const int lq   = lane >> 4;     // 0..3
  const int m0   = blockIdx.x * TM;

  if (t < 64)  sIds[t] = (m0 + t < Nrows) ? ids[m0 + t] : 0;
  if (t < 128) sLp[t >> 1][t & 1] = cls_b[t & 1];

  // accumulators, bias-initialized (r,z: b_ih+b_hh; n-gate split accN/accH)
  f32x4 accR[2][2], accZ[2][2], accN[2][2], accH[2][2];
#pragma unroll
  for (int sub = 0; sub < 2; ++sub) {
    const int nc = wn * 32 + sub * 16 + l15;
    const float br = b_ih[nc] + b_hh[nc];
    const float bz = b_ih[128 + nc] + b_hh[128 + nc];
    const float bn = b_ih[256 + nc];
    const float bh = b_hh[256 + nc];
#pragma unroll
    for (int mt = 0; mt < 2; ++mt) {
      accR[mt][sub] = (f32x4){br, br, br, br};
      accZ[mt][sub] = (f32x4){bz, bz, bz, bz};
      accN[mt][sub] = (f32x4){bn, bn, bn, bn};
      accH[mt][sub] = (f32x4){bh, bh, bh, bh};
    }
  }

  // A staging role: thread t handles row ar = t>>3, f32-quad aq = t&7
  const int  ar = t >> 3;
  const int  aq = t & 7;
  const bool av = (m0 + ar) < Nrows;
  const float* pA = emb + (size_t)(m0 + ar) * EDIM + aq * 4;
  const int  awofs = ar * 80 + aq * 8;
  const float4 fz = make_float4(0.f, 0.f, 0.f, 0.f);
  float lp0 = 0.f, lp1 = 0.f;
  float4 aCur = fz, aNxt = fz;    // emb slices C+1, C+2 in flight

  // ---- prologue: stage chunk 0 (W via glds, A via reg+cvt); prefetch slice 1 ----
  stageW<EDIM>(wib, 0, sW[0], wave, lane);
  {
    float4 a = av ? *(const float4*)pA : fz;
    const float4 c0 = *(const float4*)(cls_w + aq * 4);
    const float4 c1 = *(const float4*)(cls_w + CDIM + aq * 4);
    lp0 += a.x * c0.x + a.y * c0.y + a.z * c0.z + a.w * c0.w;
    lp1 += a.x * c1.x + a.y * c1.y + a.z * c1.z + a.w * c1.w;
    bf16x4 o = {(bf16)a.x, (bf16)a.y, (bf16)a.z, (bf16)a.w};
    *(bf16x4*)(sA[0] + awofs) = o;
    if (av) aCur = *(const float4*)(pA + 32);   // slice 1
  }
  __syncthreads();

  // ---- Phase A: 48 chunks of 32 k, sW dbuf, 1 barrier/chunk ----
  for (int C = 0; C < NCH; ++C) {
    const int cur = C & 1, nxt = cur ^ 1;
    const bool pf = (C + 1) < NCH;
    if (pf) stageW<EDIM>(wib, (C + 1) * 32, sW[nxt], wave, lane);  // 0-reg prefetch
    if (C + 2 < NCH && av) aNxt = *(const float4*)(pA + (C + 2) * 32);  // dist-2

    bf16x8 af[2];
#pragma unroll
    for (int mt = 0; mt < 2; ++mt) {
      const int m = wm * 32 + mt * 16 + l15;
      af[mt] = *(bf16x8*)(sA[cur] + m * 80 + lq * 16);
    }
#pragma unroll
    for (int g = 0; g < 3; ++g) {
#pragma unroll
      for (int sub = 0; sub < 2; ++sub) {
        const int n = g * 128 + wn * 32 + sub * 16 + l15;
        const bf16x8 bfr = *(bf16x8*)(sW[cur] + n * 64 + lq * 16);
        if (g == 0) {
          accR[0][sub] = MFMA_B16(af[0], bfr, accR[0][sub]);
          accR[1][sub] = MFMA_B16(af[1], bfr, accR[1][sub]);
        } else if (g == 1) {
          accZ[0][sub] = MFMA_B16(af[0], bfr, accZ[0][sub]);
          accZ[1][sub] = MFMA_B16(af[1], bfr, accZ[1][sub]);
        } else {
          accN[0][sub] = MFMA_B16(af[0], bfr, accN[0][sub]);
          accN[1][sub] = MFMA_B16(af[1], bfr, accN[1][sub]);
        }
      }
    }
    if (pf) {  // consume prefetched slice C+1 (loaded ~1.5 bodies ago)
      const int kc = (C + 1) * 32 + aq * 4;
      const float4 c0 = *(const float4*)(cls_w + kc);
      const float4 c1 = *(const float4*)(cls_w + CDIM + kc);
      lp0 += aCur.x * c0.x + aCur.y * c0.y + aCur.z * c0.z + aCur.w * c0.w;
      lp1 += aCur.x * c1.x + aCur.y * c1.y + aCur.z * c1.z + aCur.w * c1.w;
      bf16x4 o = {(bf16)aCur.x, (bf16)aCur.y, (bf16)aCur.z, (bf16)aCur.w};
      *(bf16x4*)(sA[nxt] + awofs) = o;
      aCur = aNxt;
    }
    __syncthreads();
  }

  // classifier emb-part: reduce over the 8 threads sharing row ar
  {
    float v0 = lp0, v1 = lp1;
    v0 += __shfl_xor(v0, 1); v0 += __shfl_xor(v0, 2); v0 += __shfl_xor(v0, 4);
    v1 += __shfl_xor(v1, 1); v1 += __shfl_xor(v1, 2); v1 += __shfl_xor(v1, 4);
    if ((lane & 7) == 0) {
      atomicAdd(&sLp[ar][0], v0);
      atomicAdd(&sLp[ar][1], v1);
    }
  }

  // ---- Phase B: gather prev -> sP (proven layout), gh over K=128 ----
  stageW<DDIM>(whb, 0, sW[0], wave, lane);   // phase-A last read was sW[1]
  {
    const int prow = t >> 5;            // 0..15
    const int pc   = t & 31;            // f32 quad: col = pc*4
#pragma unroll
    for (int p = 0; p < 4; ++p) {
      const int r = p * 16 + prow;
      const float4 v = *(const float4*)(mem + (size_t)sIds[r] * DDIM + pc * 4);
      bf16x4 o = {(bf16)v.x, (bf16)v.y, (bf16)v.z, (bf16)v.w};
      *(bf16x4*)(sP + r * 256 + ((pc << 3) ^ ((r & 7) << 4))) = o;
    }
  }
  __syncthreads();

  for (int ks = 0; ks < 4; ++ks) {
    const int cur = ks & 1, nxt = cur ^ 1;
    if (ks + 1 < 4) stageW<DDIM>(whb, (ks + 1) * 32, sW[nxt], wave, lane);
    bf16x8 af[2];
#pragma unroll
    for (int mt = 0; mt < 2; ++mt) {
      const int m = wm * 32 + mt * 16 + l15;
      const int kb = (ks * 32 + lq * 8) << 1;
      af[mt] = *(bf16x8*)(sP + m * 256 + (kb ^ ((m & 7) << 4)));
    }
#pragma unroll
    for (int g = 0; g < 3; ++g) {
#pragma unroll
      for (int sub = 0; sub < 2; ++sub) {
        const int n = g * 128 + wn * 32 + sub * 16 + l15;
        const bf16x8 bfr = *(bf16x8*)(sW[cur] + n * 64 + lq * 16);
        if (g == 0) {
          accR[0][sub] = MFMA_B16(af[0], bfr, accR[0][sub]);
          accR[1][sub] = MFMA_B16(af[1], bfr, accR[1][sub]);
        } else if (g == 1) {
          accZ[0][sub] = MFMA_B16(af[0], bfr, accZ[0][sub]);
          accZ[1][sub] = MFMA_B16(af[1], bfr, accZ[1][sub]);
        } else {
          accH[0][sub] = MFMA_B16(af[0], bfr, accH[0][sub]);
          accH[1][sub] = MFMA_B16(af[1], bfr, accH[1][sub]);
        }
      }
    }
    __syncthreads();
  }

  // ---- Epilogue: gates, scatter new_mem, classifier mem-part ----
  float lpM[8][2];
#pragma unroll
  for (int i = 0; i < 8; ++i) { lpM[i][0] = 0.f; lpM[i][1] = 0.f; }

#pragma unroll
  for (int mt = 0; mt < 2; ++mt) {
#pragma unroll
    for (int sub = 0; sub < 2; ++sub) {
      const int d = wn * 32 + sub * 16 + l15;
      const float cw0 = cls_w[EDIM + d];
      const float cw1 = cls_w[CDIM + EDIM + d];
#pragma unroll
      for (int j = 0; j < 4; ++j) {
        const int m = wm * 32 + mt * 16 + lq * 4 + j;
        const float r = sigf(accR[mt][sub][j]);
        const float z = sigf(accZ[mt][sub][j]);
        const float n = tanhf_fast(accN[mt][sub][j] + r * accH[mt][sub][j]);
        const float pv = mem[(size_t)sIds[m] * DDIM + d];
        const float nv = (1.0f - z) * n + z * pv;
        if (m0 + m < Nrows) omem[(size_t)sIds[m] * DDIM + d] = nv;
        lpM[mt * 4 + j][0] += nv * cw0;
        lpM[mt * 4 + j][1] += nv * cw1;
      }
    }
  }

#pragma unroll
  for (int i = 0; i < 8; ++i) {
#pragma unroll
    for (int c = 0; c < 2; ++c) {
      float v = lpM[i][c];
      v += __shfl_xor(v, 1); v += __shfl_xor(v, 2);
      v += __shfl_xor(v, 4); v += __shfl_xor(v, 8);
      if (l15 == 0) {
        const int m = wm * 32 + (i >> 2) * 16 + lq * 4 + (i & 3);
        atomicAdd(&sLp[m][c], v);
      }
    }
  }
  __syncthreads();

  if (t < 128) {
    const int m = t >> 1, c = t & 1;
    if (m0 + m < Nrows) logits[(size_t)(m0 + m) * 2 + c] = sLp[m][c];
  }
}

extern "C" void kernel_launch(void* const* d_in, const int* in_sizes, int n_in,
                              void* d_out, int out_size, void* d_ws, size_t ws_size,
                              hipStream_t stream) {
  const float* emb   = (const float*)d_in[0];
  const int*   ids   = (const int*)d_in[1];
  const float* mem   = (const float*)d_in[2];
  const float* w_ih  = (const float*)d_in[3];
  const float* w_hh  = (const float*)d_in[4];
  const float* b_ih  = (const float*)d_in[5];
  const float* b_hh  = (const float*)d_in[6];
  const float* cls_w = (const float*)d_in[7];
  const float* cls_b = (const float*)d_in[8];

  const int N    = in_sizes[0] / EDIM;   // 100000
  const int MAXN = in_sizes[2] / DDIM;   // 250000

  float* logits = (float*)d_out;
  float* omem   = (float*)d_out + (size_t)N * 2;
  bf16*  wib    = (bf16*)d_ws;
  bf16*  whb    = wib + 3 * DDIM * EDIM;

  // 1) blanket copy memory -> out (scatter overwrites active rows)
  hipMemcpyAsync(omem, mem, (size_t)MAXN * DDIM * sizeof(float),
                 hipMemcpyDeviceToDevice, stream);
  // 2) weights to bf16
  const int prep_threads = (3 * DDIM * EDIM + 3 * DDIM * DDIM) / 4;
  prep_convert<<<(prep_threads + 255) / 256, 256, 0, stream>>>(w_ih, w_hh, wib, whb);
  // 3) fused GRU + classifier
  gru_fused<<<(N + TM - 1) / TM, 512, 0, stream>>>(emb, ids, mem, b_ih, b_hh,
                                                   cls_w, cls_b, wib, whb,
                                                   logits, omem, N);
}